// Round 18
// baseline (623.291 us; speedup 1.0000x reference)
//
#include <hip/hip_runtime.h>
#include <hip/hip_bf16.h>
#include <math.h>
#include <stdint.h>

// Problem constants
static constexpr int Bb = 8, S = 1024, E = 1152, H = 16, D = 72;
static constexpr int N3 = 3 * E;                 // 3456
static constexpr long QKV_T = (long)Bb * H * S * D;  // 9437184 elems per tensor

typedef __attribute__((ext_vector_type(8))) short bf16x8;
typedef __attribute__((ext_vector_type(4))) short bf16x4;
typedef __attribute__((ext_vector_type(4))) float f32x4;

#define MFMA16(A, B, C) __builtin_amdgcn_mfma_f32_16x16x32_bf16(A, B, C, 0, 0, 0)

__device__ __forceinline__ short f2bf(float f) {
    __hip_bfloat16 h = __float2bfloat16(f);
    return __builtin_bit_cast(short, h);
}
// HW packed f32->bf16 (RNE)
__device__ __forceinline__ unsigned cvtpk(float lo, float hi) {
    unsigned r;
    asm("v_cvt_pk_bf16_f32 %0, %1, %2" : "=v"(r) : "v"(lo), "v"(hi));
    return r;
}

__device__ __forceinline__ void gload_lds16(const void* g, void* l) {
    __builtin_amdgcn_global_load_lds(
        (const __attribute__((address_space(1))) unsigned int*)g,
        (__attribute__((address_space(3))) unsigned int*)l, 16, 0, 0);
}

// ---------------------------------------------------------------------------
// Kernel A: transpose+convert.  W[K][N] f32 -> WT[N][K] bf16.
// ---------------------------------------------------------------------------
__global__ __launch_bounds__(256)
void wt_conv(const float* __restrict__ W, short* __restrict__ WT, int K, int N)
{
    __shared__ float tt[32][33];
    const int n0 = blockIdx.x * 32, k0 = blockIdx.y * 32;
    const int t = threadIdx.x;
    {
        int r = t >> 3, c4 = (t & 7) * 4;
        float4 v = *reinterpret_cast<const float4*>(W + (long)(k0 + r) * N + n0 + c4);
        tt[r][c4 + 0] = v.x; tt[r][c4 + 1] = v.y; tt[r][c4 + 2] = v.z; tt[r][c4 + 3] = v.w;
    }
    __syncthreads();
    {
        int n = t >> 3, k4 = (t & 7) * 4;
        bf16x4 o = {f2bf(tt[k4 + 0][n]), f2bf(tt[k4 + 1][n]),
                    f2bf(tt[k4 + 2][n]), f2bf(tt[k4 + 3][n])};
        *reinterpret_cast<bf16x4*>(WT + (long)(n0 + n) * K + k0 + k4) = o;
    }
}

// ---------------------------------------------------------------------------
// Kernel B: convert f32 -> bf16.  n4 = element_count / 4.
// ---------------------------------------------------------------------------
__global__ __launch_bounds__(256)
void tobf16(const float* __restrict__ X, short* __restrict__ Y, long n4)
{
    for (long i = (long)blockIdx.x * 256 + threadIdx.x; i < n4; i += (long)gridDim.x * 256) {
        float4 v = reinterpret_cast<const float4*>(X)[i];
        uint2 p = {cvtpk(v.x, v.y), cvtpk(v.z, v.w)};
        reinterpret_cast<uint2*>(Y)[i] = p;
    }
}

// ---------------------------------------------------------------------------
// Kernel 1: projection for ONE of q/k/v.  C[8192,1152] = X(bf16) @ Wg + bg.
// Plain bf16 MFMA; all staging full-wave global_load_lds.
// Grid (64 m, 9 n): A-tile sharers at linear-ID stride 64 -> same XCD.
// which==2 (V): stored transposed [bh][d][s], chunk-swizzled within each
// 64-s block (chunk ^= d&7) so attn can load linearly + XOR on read.
// ---------------------------------------------------------------------------
__global__ __launch_bounds__(256)
void qkv_proj_one(const short* __restrict__ Xb, const short* __restrict__ WTn,
                  const float* __restrict__ bias, short* __restrict__ qkvW, int which)
{
    __shared__ short aT[128][32], bW[128][32];
    const int tid = threadIdx.x, lane = tid & 63, w = tid >> 6;
    const int c = lane & 15, g = lane >> 4;
    const int m0 = blockIdx.x * 128, n0 = blockIdx.y * 128;
    const int wm = (w >> 1) * 64, wn = (w & 1) * 64;
    const int lrow = lane >> 2, lch = (lane & 3) * 8;

    f32x4 acc[4][4] = {};

    for (int k0 = 0; k0 < E; k0 += 32) {
        __syncthreads();
        for (int t = 0; t < 2; ++t) {
            int row = w * 32 + t * 16;
            gload_lds16(Xb + (long)(m0 + row + lrow) * E + k0 + lch, &aT[row][0]);
            gload_lds16(WTn + (long)(n0 + row + lrow) * E + k0 + lch, &bW[row][0]);
        }
        __syncthreads();

        bf16x8 af[4], bh[4];
        for (int i = 0; i < 4; ++i) {
            af[i] = *reinterpret_cast<const bf16x8*>(&aT[wm + i * 16 + c][g * 8]);
            bh[i] = *reinterpret_cast<const bf16x8*>(&bW[wn + i * 16 + c][g * 8]);
        }
        for (int i = 0; i < 4; ++i)
            for (int j = 0; j < 4; ++j)
                acc[i][j] = MFMA16(af[i], bh[j], acc[i][j]);
    }

    for (int j = 0; j < 4; ++j) {
        int n = n0 + wn + j * 16 + c;      // 0..1151
        float bv = bias[n];
        int hh = n / D, dd = n % D;
        if (which < 2) {
            for (int i = 0; i < 4; ++i) {
                int rowb = m0 + wm + i * 16 + g * 4;
                for (int r = 0; r < 4; ++r) {
                    int row = rowb + r;
                    int b = row >> 10, s = row & 1023;
                    qkvW[((long)(b * H + hh) * S + s) * D + dd] = f2bf(acc[i][j][r] + bv);
                }
            }
        } else {
            int cx = dd & 7;
            for (int i = 0; i < 4; ++i) {
                int srow = m0 + wm + i * 16 + g * 4;   // 4 consecutive s
                int b = srow >> 10, s = srow & 1023;
                int sw = (s & ~63) | ((((s >> 3) & 7) ^ cx) << 3) | (s & 7);
                bf16x4 pk = {f2bf(acc[i][j][0] + bv), f2bf(acc[i][j][1] + bv),
                             f2bf(acc[i][j][2] + bv), f2bf(acc[i][j][3] + bv)};
                *reinterpret_cast<bf16x4*>(&qkvW[((long)(b * H + hh) * D + dd) * S + sw]) = pk;
            }
        }
    }
}

// ---------------------------------------------------------------------------
// Kernel 2: flash attention, q-tile 256, 8 waves/block, grid (bh, 4).
// Swapped-operand (S^T = K Q^T) + fixed-offset softmax p = 2^(s*K2 - 4)
// (shift-invariant, scores bounded -> no max tracking).
// l via MFMA ones-row (V^T pad row 72 = 1.0 -> accO[4] reg0 @ lanes 32..47).
// i-SPLIT (r18): softmax(i) -> PV(i) sequentially; PT is per-wave private so
// no barrier; PT halves to [8 waves][16][36] dwords -> LDS 37936 B ->
// 4 blocks/CU (32 waves/CU, was 2 blocks/16 waves).
// LDS (shorts): K[64][72]@0 | guard 24 @4608 | V[80][64]@4632 (row72=ones,
// 73..79 zero) | PT dwords @9752 (4608 dw).  Total 37936 B.
// ---------------------------------------------------------------------------
__global__ __launch_bounds__(512, 8)
void attn_fwd(const short* __restrict__ qkv, short* __restrict__ attn)
{
    __shared__ short smem[18968];
    unsigned* PT = reinterpret_cast<unsigned*>(smem + 9752);
    const int tid = threadIdx.x, lane = tid & 63, w = tid >> 6;   // w: 0..7
    const int c = lane & 15, g = lane >> 4;
    const int bh = blockIdx.x;
    const int q0 = blockIdx.y * 256;
    const int b = bh >> 4, h = bh & 15;

    const short* Qb = qkv + (long)bh * (S * D);
    const short* Kb = qkv + QKV_T + (long)bh * (S * D);
    const short* Vt = qkv + 2 * QKV_T + (long)bh * ((long)D * S);

    // zero K guard; V pad: row 72 = bf16 1.0 (l-accumulator row), 73..79 = 0
    if (tid < 24) smem[4608 + tid] = 0;
    if (tid < 512) smem[9240 + tid] = (tid < 64) ? (short)0x3F80 : (short)0;

    // staging descriptors (rounds r = w + rr*8, r < 9)
    const short* kg[2]; const short* vg[2]; int ldsOff[2];
    #pragma unroll
    for (int rr = 0; rr < 2; ++rr) {
        int r = w + rr * 8;
        int id = r * 64 + lane;
        kg[rr] = Kb + id * 8;
        vg[rr] = Vt + (long)(id >> 3) * S + (id & 7) * 8;
        ldsOff[rr] = id * 8;
    }

    // Q fragments (B-operand), d-tail zero for g>0
    bf16x8 qf[2][3];
    const bf16x8 zf = {};
    for (int i = 0; i < 2; ++i) {
        const short* qr = Qb + (long)(q0 + w * 32 + i * 16 + c) * D;
        qf[i][0] = *reinterpret_cast<const bf16x8*>(qr + g * 8);
        qf[i][1] = *reinterpret_cast<const bf16x8*>(qr + 32 + g * 8);
        qf[i][2] = (g == 0) ? *reinterpret_cast<const bf16x8*>(qr + 64) : zf;
    }

    const float K2 = 0.17003594880664552f;   // 72^-0.5 * log2(e)
    const float M2 = 4.0f;                   // fixed exp2-domain offset
    f32x4 accO[5][2] = {};

    for (int kt = 0; kt < 16; ++kt) {
        __syncthreads();   // prior tile's reads done
        #pragma unroll
        for (int rr = 0; rr < 2; ++rr) {
            if (w + rr * 8 < 9) {
                gload_lds16(kg[rr], &smem[ldsOff[rr]]);
                gload_lds16(vg[rr], &smem[4632 + ldsOff[rr]]);
                kg[rr] += 64 * D;
                vg[rr] += 64;
            }
        }
        __syncthreads();

        // ---- S^T[k'][q] = K Q^T (both i) ----
        f32x4 sT[4][2] = {};
        for (int dc = 0; dc < 3; ++dc) {
            for (int j = 0; j < 4; ++j) {
                bf16x8 kf = *reinterpret_cast<const bf16x8*>(
                    &smem[(j * 16 + c) * 72 + dc * 32 + g * 8]);
                for (int i = 0; i < 2; ++i)
                    sT[j][i] = MFMA16(kf, qf[i][dc], sT[j][i]);
            }
        }

        // ---- per-i: fixed-offset softmax -> PT (wave-private) -> PV ----
        for (int i = 0; i < 2; ++i) {
            for (int j = 0; j < 4; ++j) {
                float p0 = exp2f(fmaf(sT[j][i][0], K2, -M2));
                float p1 = exp2f(fmaf(sT[j][i][1], K2, -M2));
                float p2 = exp2f(fmaf(sT[j][i][2], K2, -M2));
                float p3 = exp2f(fmaf(sT[j][i][3], K2, -M2));
                uint2 pw = {cvtpk(p0, p1), cvtpk(p2, p3)};
                *reinterpret_cast<uint2*>(
                    &PT[(w * 16 + c) * 36 + j * 8 + g * 2]) = pw;
            }
            for (int ks = 0; ks < 2; ++ks) {
                bf16x8 pf = *reinterpret_cast<const bf16x8*>(
                    &PT[(w * 16 + c) * 36 + ks * 16 + g * 4]);
                for (int n = 0; n < 5; ++n) {
                    bf16x8 vf = *reinterpret_cast<const bf16x8*>(
                        &smem[4632 + (n * 16 + c) * 64 + (((ks * 4 + g) ^ (c & 7))) * 8]);
                    accO[n][i] = MFMA16(vf, pf, accO[n][i]);
                }
            }
        }
    }

    // ---- epilogue: l = accO[4][i][0] at lane 32+c; stage O[256][72], burst ----
    __syncthreads();   // all waves done reading K/V LDS
    for (int i = 0; i < 2; ++i) {
        float lv = __shfl(accO[4][i][0], 32 + c);
        float inv = 1.f / lv;
        int ql = w * 32 + i * 16 + c;          // 0..255
        for (int n = 0; n < 5; ++n) {
            int d0 = n * 16 + g * 4;
            if (d0 >= D) continue;
            uint2 pk = {cvtpk(accO[n][i][0] * inv, accO[n][i][1] * inv),
                        cvtpk(accO[n][i][2] * inv, accO[n][i][3] * inv)};
            *reinterpret_cast<uint2*>(&smem[ql * 72 + d0]) = pk;
        }
    }
    __syncthreads();
    {
        const long rowbase = (long)(b * S + q0) * E + h * D;
        for (int ch = tid; ch < 2304; ch += 512) {
            int row = ch / 9, off = (ch % 9) * 8;
            *reinterpret_cast<uint4*>(attn + rowbase + (long)row * E + off) =
                *reinterpret_cast<const uint4*>(&smem[row * 72 + off]);
        }
    }
}

// ---------------------------------------------------------------------------
// Kernel 3: out projection.  out[8192,1152] = attn(bf16) @ WTo(bf16) + b.
// Grid (64 m, 9 n) — same XCD-locality argument as qkv_proj_one.
// ---------------------------------------------------------------------------
__global__ __launch_bounds__(256)
void out_proj(const short* __restrict__ Aat, const short* __restrict__ WTo,
              const float* __restrict__ bias, float* __restrict__ out)
{
    __shared__ short aT[128][32], bT[128][32];
    const int tid = threadIdx.x, lane = tid & 63, w = tid >> 6;
    const int c = lane & 15, g = lane >> 4;
    const int m0 = blockIdx.x * 128, n0 = blockIdx.y * 128;
    const int wm = (w >> 1) * 64, wn = (w & 1) * 64;
    const int lrow = lane >> 2, lch = (lane & 3) * 8;

    f32x4 acc[4][4] = {};
    for (int k0 = 0; k0 < E; k0 += 32) {
        __syncthreads();
        for (int t = 0; t < 2; ++t) {
            int row = w * 32 + t * 16;
            gload_lds16(Aat + (long)(m0 + row + lrow) * E + k0 + lch, &aT[row][0]);
            gload_lds16(WTo + (long)(n0 + row + lrow) * E + k0 + lch, &bT[row][0]);
        }
        __syncthreads();

        bf16x8 af[4], bf[4];
        for (int i = 0; i < 4; ++i) {
            af[i] = *reinterpret_cast<const bf16x8*>(&aT[wm + i * 16 + c][g * 8]);
            bf[i] = *reinterpret_cast<const bf16x8*>(&bT[wn + i * 16 + c][g * 8]);
        }
        for (int i = 0; i < 4; ++i)
            for (int j = 0; j < 4; ++j)
                acc[i][j] = MFMA16(af[i], bf[j], acc[i][j]);
    }

    for (int j = 0; j < 4; ++j) {
        int n = n0 + wn + j * 16 + c;
        float bv = bias[n];
        for (int i = 0; i < 4; ++i)
            for (int r = 0; r < 4; ++r) {
                int row = m0 + wm + i * 16 + g * 4 + r;
                out[(long)row * E + n] = acc[i][j][r] + bv;
            }
    }
}

// ---------------------------------------------------------------------------
// Workspace (shorts), peak 83.46 MB:
//   Q[QKV_T] | K[QKV_T] | V^T[QKV_T] | A[QKV_T] | WT[3456*1152]
// A slot: bf16-converted input during projections (conv->proj interleaved to
// keep the 18.9 MB input hot in L2 — r17 showed fusing the convs evicts it),
// then attn output.  WTo aliases WT.
// ---------------------------------------------------------------------------
extern "C" void kernel_launch(void* const* d_in, const int* in_sizes, int n_in,
                              void* d_out, int out_size, void* d_ws, size_t ws_size,
                              hipStream_t stream)
{
    const float* qin   = (const float*)d_in[0];
    const float* kin   = (const float*)d_in[1];
    const float* vin   = (const float*)d_in[2];
    const float* w_in  = (const float*)d_in[3];
    const float* b_in  = (const float*)d_in[4];
    const float* w_out = (const float*)d_in[5];
    const float* b_out = (const float*)d_in[6];

    short* ws  = (short*)d_ws;
    short* Q   = ws;
    short* K   = ws + QKV_T;
    short* V   = ws + 2 * QKV_T;
    short* A   = ws + 3 * QKV_T;   // converted input, then attn output
    short* WT  = ws + 4 * QKV_T;
    short* WTo = WT;
    float* out = (float*)d_out;

    wt_conv<<<dim3(108, 36), 256, 0, stream>>>(w_in, WT, E, N3);

    tobf16<<<2048, 256, 0, stream>>>(vin, A, QKV_T / 4);
    qkv_proj_one<<<dim3(64, 9), 256, 0, stream>>>(A, WT + 2L * E * E, b_in + 2 * E, V, 2);
    tobf16<<<2048, 256, 0, stream>>>(kin, A, QKV_T / 4);
    qkv_proj_one<<<dim3(64, 9), 256, 0, stream>>>(A, WT + 1L * E * E, b_in + E, K, 1);
    tobf16<<<2048, 256, 0, stream>>>(qin, A, QKV_T / 4);
    qkv_proj_one<<<dim3(64, 9), 256, 0, stream>>>(A, WT, b_in, Q, 0);

    attn_fwd<<<dim3(128, 4), 512, 0, stream>>>(ws, A);
    wt_conv<<<dim3(36, 36), 256, 0, stream>>>(w_out, WTo, E, E);
    out_proj<<<dim3(64, 9), 256, 0, stream>>>(A, WTo, b_out, out);
}

// Round 19
// 239.902 us; speedup vs baseline: 2.5981x; 2.5981x over previous
//
#include <hip/hip_runtime.h>
#include <hip/hip_bf16.h>
#include <math.h>
#include <stdint.h>

// Problem constants
static constexpr int Bb = 8, S = 1024, E = 1152, H = 16, D = 72;
static constexpr int N3 = 3 * E;                 // 3456
static constexpr long QKV_T = (long)Bb * H * S * D;  // 9437184 elems per tensor

typedef __attribute__((ext_vector_type(8))) short bf16x8;
typedef __attribute__((ext_vector_type(4))) short bf16x4;
typedef __attribute__((ext_vector_type(4))) float f32x4;

#define MFMA16(A, B, C) __builtin_amdgcn_mfma_f32_16x16x32_bf16(A, B, C, 0, 0, 0)

__device__ __forceinline__ short f2bf(float f) {
    __hip_bfloat16 h = __float2bfloat16(f);
    return __builtin_bit_cast(short, h);
}
// HW packed f32->bf16 (RNE)
__device__ __forceinline__ unsigned cvtpk(float lo, float hi) {
    unsigned r;
    asm("v_cvt_pk_bf16_f32 %0, %1, %2" : "=v"(r) : "v"(lo), "v"(hi));
    return r;
}

__device__ __forceinline__ void gload_lds16(const void* g, void* l) {
    __builtin_amdgcn_global_load_lds(
        (const __attribute__((address_space(1))) unsigned int*)g,
        (__attribute__((address_space(3))) unsigned int*)l, 16, 0, 0);
}

// ---------------------------------------------------------------------------
// Kernel A: transpose+convert.  W[K][N] f32 -> WT[N][K] bf16.
// ---------------------------------------------------------------------------
__global__ __launch_bounds__(256)
void wt_conv(const float* __restrict__ W, short* __restrict__ WT, int K, int N)
{
    __shared__ float tt[32][33];
    const int n0 = blockIdx.x * 32, k0 = blockIdx.y * 32;
    const int t = threadIdx.x;
    {
        int r = t >> 3, c4 = (t & 7) * 4;
        float4 v = *reinterpret_cast<const float4*>(W + (long)(k0 + r) * N + n0 + c4);
        tt[r][c4 + 0] = v.x; tt[r][c4 + 1] = v.y; tt[r][c4 + 2] = v.z; tt[r][c4 + 3] = v.w;
    }
    __syncthreads();
    {
        int n = t >> 3, k4 = (t & 7) * 4;
        bf16x4 o = {f2bf(tt[k4 + 0][n]), f2bf(tt[k4 + 1][n]),
                    f2bf(tt[k4 + 2][n]), f2bf(tt[k4 + 3][n])};
        *reinterpret_cast<bf16x4*>(WT + (long)(n0 + n) * K + k0 + k4) = o;
    }
}

// ---------------------------------------------------------------------------
// Kernel B: convert f32 -> bf16.  n4 = element_count / 4.
// ---------------------------------------------------------------------------
__global__ __launch_bounds__(256)
void tobf16(const float* __restrict__ X, short* __restrict__ Y, long n4)
{
    for (long i = (long)blockIdx.x * 256 + threadIdx.x; i < n4; i += (long)gridDim.x * 256) {
        float4 v = reinterpret_cast<const float4*>(X)[i];
        uint2 p = {cvtpk(v.x, v.y), cvtpk(v.z, v.w)};
        reinterpret_cast<uint2*>(Y)[i] = p;
    }
}

// ---------------------------------------------------------------------------
// Kernel 1: projection for ONE of q/k/v.  C[8192,1152] = X(bf16) @ Wg + bg.
// Plain bf16 MFMA; all staging full-wave global_load_lds.
// Grid (64 m, 9 n): A-tile sharers at linear-ID stride 64 -> same XCD.
// which==2 (V): stored transposed [bh][d][s], chunk-swizzled within each
// 64-s block (chunk ^= d&7) so attn can load linearly + XOR on read.
// ---------------------------------------------------------------------------
__global__ __launch_bounds__(256)
void qkv_proj_one(const short* __restrict__ Xb, const short* __restrict__ WTn,
                  const float* __restrict__ bias, short* __restrict__ qkvW, int which)
{
    __shared__ short aT[128][32], bW[128][32];
    const int tid = threadIdx.x, lane = tid & 63, w = tid >> 6;
    const int c = lane & 15, g = lane >> 4;
    const int m0 = blockIdx.x * 128, n0 = blockIdx.y * 128;
    const int wm = (w >> 1) * 64, wn = (w & 1) * 64;
    const int lrow = lane >> 2, lch = (lane & 3) * 8;

    f32x4 acc[4][4] = {};

    for (int k0 = 0; k0 < E; k0 += 32) {
        __syncthreads();
        for (int t = 0; t < 2; ++t) {
            int row = w * 32 + t * 16;
            gload_lds16(Xb + (long)(m0 + row + lrow) * E + k0 + lch, &aT[row][0]);
            gload_lds16(WTn + (long)(n0 + row + lrow) * E + k0 + lch, &bW[row][0]);
        }
        __syncthreads();

        bf16x8 af[4], bh[4];
        for (int i = 0; i < 4; ++i) {
            af[i] = *reinterpret_cast<const bf16x8*>(&aT[wm + i * 16 + c][g * 8]);
            bh[i] = *reinterpret_cast<const bf16x8*>(&bW[wn + i * 16 + c][g * 8]);
        }
        for (int i = 0; i < 4; ++i)
            for (int j = 0; j < 4; ++j)
                acc[i][j] = MFMA16(af[i], bh[j], acc[i][j]);
    }

    for (int j = 0; j < 4; ++j) {
        int n = n0 + wn + j * 16 + c;      // 0..1151
        float bv = bias[n];
        int hh = n / D, dd = n % D;
        if (which < 2) {
            for (int i = 0; i < 4; ++i) {
                int rowb = m0 + wm + i * 16 + g * 4;
                for (int r = 0; r < 4; ++r) {
                    int row = rowb + r;
                    int b = row >> 10, s = row & 1023;
                    qkvW[((long)(b * H + hh) * S + s) * D + dd] = f2bf(acc[i][j][r] + bv);
                }
            }
        } else {
            int cx = dd & 7;
            for (int i = 0; i < 4; ++i) {
                int srow = m0 + wm + i * 16 + g * 4;   // 4 consecutive s
                int b = srow >> 10, s = srow & 1023;
                int sw = (s & ~63) | ((((s >> 3) & 7) ^ cx) << 3) | (s & 7);
                bf16x4 pk = {f2bf(acc[i][j][0] + bv), f2bf(acc[i][j][1] + bv),
                             f2bf(acc[i][j][2] + bv), f2bf(acc[i][j][3] + bv)};
                *reinterpret_cast<bf16x4*>(&qkvW[((long)(b * H + hh) * D + dd) * S + sw]) = pk;
            }
        }
    }
}

// ---------------------------------------------------------------------------
// Kernel 2: flash attention, q-tile 256, 8 waves/block, grid (bh, 4).
// Swapped-operand (S^T = K Q^T) + fixed-offset softmax p = 2^(s*K2 - 4).
// l via MFMA ones-row (V^T pad row 72 = 1.0 -> accO[4] reg0 @ lanes 32..47).
// i-split: softmax(i) -> PV(i), PT per-wave private, LDS 37936 B.
// launch_bounds (512, 4): r18's (512,8) clamped VGPR to 64-total -> spilled
// accumulators to scratch (VGPR_Count 32, FETCH 790 MB, 6x slower).  With 4
// the allocator keeps ~64-72 VGPRs; occupancy comes from LDS (4 blocks/CU).
// ---------------------------------------------------------------------------
__global__ __launch_bounds__(512, 4)
void attn_fwd(const short* __restrict__ qkv, short* __restrict__ attn)
{
    __shared__ short smem[18968];
    unsigned* PT = reinterpret_cast<unsigned*>(smem + 9752);
    const int tid = threadIdx.x, lane = tid & 63, w = tid >> 6;   // w: 0..7
    const int c = lane & 15, g = lane >> 4;
    const int bh = blockIdx.x;
    const int q0 = blockIdx.y * 256;
    const int b = bh >> 4, h = bh & 15;

    const short* Qb = qkv + (long)bh * (S * D);
    const short* Kb = qkv + QKV_T + (long)bh * (S * D);
    const short* Vt = qkv + 2 * QKV_T + (long)bh * ((long)D * S);

    // zero K guard; V pad: row 72 = bf16 1.0 (l-accumulator row), 73..79 = 0
    if (tid < 24) smem[4608 + tid] = 0;
    if (tid < 512) smem[9240 + tid] = (tid < 64) ? (short)0x3F80 : (short)0;

    // staging descriptors (rounds r = w + rr*8, r < 9)
    const short* kg[2]; const short* vg[2]; int ldsOff[2];
    #pragma unroll
    for (int rr = 0; rr < 2; ++rr) {
        int r = w + rr * 8;
        int id = r * 64 + lane;
        kg[rr] = Kb + id * 8;
        vg[rr] = Vt + (long)(id >> 3) * S + (id & 7) * 8;
        ldsOff[rr] = id * 8;
    }

    // Q fragments (B-operand), d-tail zero for g>0
    bf16x8 qf[2][3];
    const bf16x8 zf = {};
    for (int i = 0; i < 2; ++i) {
        const short* qr = Qb + (long)(q0 + w * 32 + i * 16 + c) * D;
        qf[i][0] = *reinterpret_cast<const bf16x8*>(qr + g * 8);
        qf[i][1] = *reinterpret_cast<const bf16x8*>(qr + 32 + g * 8);
        qf[i][2] = (g == 0) ? *reinterpret_cast<const bf16x8*>(qr + 64) : zf;
    }

    const float K2 = 0.17003594880664552f;   // 72^-0.5 * log2(e)
    const float M2 = 4.0f;                   // fixed exp2-domain offset
    f32x4 accO[5][2] = {};

    for (int kt = 0; kt < 16; ++kt) {
        __syncthreads();   // prior tile's reads done
        #pragma unroll
        for (int rr = 0; rr < 2; ++rr) {
            if (w + rr * 8 < 9) {
                gload_lds16(kg[rr], &smem[ldsOff[rr]]);
                gload_lds16(vg[rr], &smem[4632 + ldsOff[rr]]);
                kg[rr] += 64 * D;
                vg[rr] += 64;
            }
        }
        __syncthreads();

        // ---- S^T[k'][q] = K Q^T (both i) ----
        f32x4 sT[4][2] = {};
        for (int dc = 0; dc < 3; ++dc) {
            for (int j = 0; j < 4; ++j) {
                bf16x8 kf = *reinterpret_cast<const bf16x8*>(
                    &smem[(j * 16 + c) * 72 + dc * 32 + g * 8]);
                for (int i = 0; i < 2; ++i)
                    sT[j][i] = MFMA16(kf, qf[i][dc], sT[j][i]);
            }
        }

        // ---- per-i: fixed-offset softmax -> PT (wave-private) -> PV ----
        for (int i = 0; i < 2; ++i) {
            for (int j = 0; j < 4; ++j) {
                float p0 = exp2f(fmaf(sT[j][i][0], K2, -M2));
                float p1 = exp2f(fmaf(sT[j][i][1], K2, -M2));
                float p2 = exp2f(fmaf(sT[j][i][2], K2, -M2));
                float p3 = exp2f(fmaf(sT[j][i][3], K2, -M2));
                uint2 pw = {cvtpk(p0, p1), cvtpk(p2, p3)};
                *reinterpret_cast<uint2*>(
                    &PT[(w * 16 + c) * 36 + j * 8 + g * 2]) = pw;
            }
            for (int ks = 0; ks < 2; ++ks) {
                bf16x8 pf = *reinterpret_cast<const bf16x8*>(
                    &PT[(w * 16 + c) * 36 + ks * 16 + g * 4]);
                for (int n = 0; n < 5; ++n) {
                    bf16x8 vf = *reinterpret_cast<const bf16x8*>(
                        &smem[4632 + (n * 16 + c) * 64 + (((ks * 4 + g) ^ (c & 7))) * 8]);
                    accO[n][i] = MFMA16(vf, pf, accO[n][i]);
                }
            }
        }
    }

    // ---- epilogue: l = accO[4][i][0] at lane 32+c; stage O[256][72], burst ----
    __syncthreads();   // all waves done reading K/V LDS
    for (int i = 0; i < 2; ++i) {
        float lv = __shfl(accO[4][i][0], 32 + c);
        float inv = 1.f / lv;
        int ql = w * 32 + i * 16 + c;          // 0..255
        for (int n = 0; n < 5; ++n) {
            int d0 = n * 16 + g * 4;
            if (d0 >= D) continue;
            uint2 pk = {cvtpk(accO[n][i][0] * inv, accO[n][i][1] * inv),
                        cvtpk(accO[n][i][2] * inv, accO[n][i][3] * inv)};
            *reinterpret_cast<uint2*>(&smem[ql * 72 + d0]) = pk;
        }
    }
    __syncthreads();
    {
        const long rowbase = (long)(b * S + q0) * E + h * D;
        for (int ch = tid; ch < 2304; ch += 512) {
            int row = ch / 9, off = (ch % 9) * 8;
            *reinterpret_cast<uint4*>(attn + rowbase + (long)row * E + off) =
                *reinterpret_cast<const uint4*>(&smem[row * 72 + off]);
        }
    }
}

// ---------------------------------------------------------------------------
// Kernel 3: out projection.  out[8192,1152] = attn(bf16) @ WTo(bf16) + b.
// Grid (64 m, 9 n) — same XCD-locality argument as qkv_proj_one.
// ---------------------------------------------------------------------------
__global__ __launch_bounds__(256)
void out_proj(const short* __restrict__ Aat, const short* __restrict__ WTo,
              const float* __restrict__ bias, float* __restrict__ out)
{
    __shared__ short aT[128][32], bT[128][32];
    const int tid = threadIdx.x, lane = tid & 63, w = tid >> 6;
    const int c = lane & 15, g = lane >> 4;
    const int m0 = blockIdx.x * 128, n0 = blockIdx.y * 128;
    const int wm = (w >> 1) * 64, wn = (w & 1) * 64;
    const int lrow = lane >> 2, lch = (lane & 3) * 8;

    f32x4 acc[4][4] = {};
    for (int k0 = 0; k0 < E; k0 += 32) {
        __syncthreads();
        for (int t = 0; t < 2; ++t) {
            int row = w * 32 + t * 16;
            gload_lds16(Aat + (long)(m0 + row + lrow) * E + k0 + lch, &aT[row][0]);
            gload_lds16(WTo + (long)(n0 + row + lrow) * E + k0 + lch, &bT[row][0]);
        }
        __syncthreads();

        bf16x8 af[4], bf[4];
        for (int i = 0; i < 4; ++i) {
            af[i] = *reinterpret_cast<const bf16x8*>(&aT[wm + i * 16 + c][g * 8]);
            bf[i] = *reinterpret_cast<const bf16x8*>(&bT[wn + i * 16 + c][g * 8]);
        }
        for (int i = 0; i < 4; ++i)
            for (int j = 0; j < 4; ++j)
                acc[i][j] = MFMA16(af[i], bf[j], acc[i][j]);
    }

    for (int j = 0; j < 4; ++j) {
        int n = n0 + wn + j * 16 + c;
        float bv = bias[n];
        for (int i = 0; i < 4; ++i)
            for (int r = 0; r < 4; ++r) {
                int row = m0 + wm + i * 16 + g * 4 + r;
                out[(long)row * E + n] = acc[i][j][r] + bv;
            }
    }
}

// ---------------------------------------------------------------------------
// Workspace (shorts), peak 83.46 MB:
//   Q[QKV_T] | K[QKV_T] | V^T[QKV_T] | A[QKV_T] | WT[3456*1152]
// A slot: bf16-converted input during projections (conv->proj interleaved to
// keep the 18.9 MB input hot in L2), then attn output.  WTo aliases WT.
// ---------------------------------------------------------------------------
extern "C" void kernel_launch(void* const* d_in, const int* in_sizes, int n_in,
                              void* d_out, int out_size, void* d_ws, size_t ws_size,
                              hipStream_t stream)
{
    const float* qin   = (const float*)d_in[0];
    const float* kin   = (const float*)d_in[1];
    const float* vin   = (const float*)d_in[2];
    const float* w_in  = (const float*)d_in[3];
    const float* b_in  = (const float*)d_in[4];
    const float* w_out = (const float*)d_in[5];
    const float* b_out = (const float*)d_in[6];

    short* ws  = (short*)d_ws;
    short* Q   = ws;
    short* K   = ws + QKV_T;
    short* V   = ws + 2 * QKV_T;
    short* A   = ws + 3 * QKV_T;   // converted input, then attn output
    short* WT  = ws + 4 * QKV_T;
    short* WTo = WT;
    float* out = (float*)d_out;

    wt_conv<<<dim3(108, 36), 256, 0, stream>>>(w_in, WT, E, N3);

    tobf16<<<2048, 256, 0, stream>>>(vin, A, QKV_T / 4);
    qkv_proj_one<<<dim3(64, 9), 256, 0, stream>>>(A, WT + 2L * E * E, b_in + 2 * E, V, 2);
    tobf16<<<2048, 256, 0, stream>>>(kin, A, QKV_T / 4);
    qkv_proj_one<<<dim3(64, 9), 256, 0, stream>>>(A, WT + 1L * E * E, b_in + E, K, 1);
    tobf16<<<2048, 256, 0, stream>>>(qin, A, QKV_T / 4);
    qkv_proj_one<<<dim3(64, 9), 256, 0, stream>>>(A, WT, b_in, Q, 0);

    attn_fwd<<<dim3(128, 4), 512, 0, stream>>>(ws, A);
    wt_conv<<<dim3(36, 36), 256, 0, stream>>>(w_out, WTo, E, E);
    out_proj<<<dim3(64, 9), 256, 0, stream>>>(A, WTo, b_out, out);
}

// Round 20
// 235.462 us; speedup vs baseline: 2.6471x; 1.0189x over previous
//
#include <hip/hip_runtime.h>
#include <hip/hip_bf16.h>
#include <math.h>
#include <stdint.h>

// Problem constants
static constexpr int Bb = 8, S = 1024, E = 1152, H = 16, D = 72;
static constexpr int N3 = 3 * E;                 // 3456
static constexpr long QKV_T = (long)Bb * H * S * D;  // 9437184 elems per tensor

typedef __attribute__((ext_vector_type(8))) short bf16x8;
typedef __attribute__((ext_vector_type(4))) short bf16x4;
typedef __attribute__((ext_vector_type(4))) float f32x4;

#define MFMA16(A, B, C) __builtin_amdgcn_mfma_f32_16x16x32_bf16(A, B, C, 0, 0, 0)

__device__ __forceinline__ short f2bf(float f) {
    __hip_bfloat16 h = __float2bfloat16(f);
    return __builtin_bit_cast(short, h);
}
// HW packed f32->bf16 (RNE)
__device__ __forceinline__ unsigned cvtpk(float lo, float hi) {
    unsigned r;
    asm("v_cvt_pk_bf16_f32 %0, %1, %2" : "=v"(r) : "v"(lo), "v"(hi));
    return r;
}

__device__ __forceinline__ void gload_lds16(const void* g, void* l) {
    __builtin_amdgcn_global_load_lds(
        (const __attribute__((address_space(1))) unsigned int*)g,
        (__attribute__((address_space(3))) unsigned int*)l, 16, 0, 0);
}

// ---------------------------------------------------------------------------
// Kernel A: transpose+convert.  W[K][N] f32 -> WT[N][K] bf16.
// ---------------------------------------------------------------------------
__global__ __launch_bounds__(256)
void wt_conv(const float* __restrict__ W, short* __restrict__ WT, int K, int N)
{
    __shared__ float tt[32][33];
    const int n0 = blockIdx.x * 32, k0 = blockIdx.y * 32;
    const int t = threadIdx.x;
    {
        int r = t >> 3, c4 = (t & 7) * 4;
        float4 v = *reinterpret_cast<const float4*>(W + (long)(k0 + r) * N + n0 + c4);
        tt[r][c4 + 0] = v.x; tt[r][c4 + 1] = v.y; tt[r][c4 + 2] = v.z; tt[r][c4 + 3] = v.w;
    }
    __syncthreads();
    {
        int n = t >> 3, k4 = (t & 7) * 4;
        bf16x4 o = {f2bf(tt[k4 + 0][n]), f2bf(tt[k4 + 1][n]),
                    f2bf(tt[k4 + 2][n]), f2bf(tt[k4 + 3][n])};
        *reinterpret_cast<bf16x4*>(WT + (long)(n0 + n) * K + k0 + k4) = o;
    }
}

// ---------------------------------------------------------------------------
// Kernel B: convert f32 -> bf16.  n4 = element_count / 4.
// ---------------------------------------------------------------------------
__global__ __launch_bounds__(256)
void tobf16(const float* __restrict__ X, short* __restrict__ Y, long n4)
{
    for (long i = (long)blockIdx.x * 256 + threadIdx.x; i < n4; i += (long)gridDim.x * 256) {
        float4 v = reinterpret_cast<const float4*>(X)[i];
        uint2 p = {cvtpk(v.x, v.y), cvtpk(v.z, v.w)};
        reinterpret_cast<uint2*>(Y)[i] = p;
    }
}

// ---------------------------------------------------------------------------
// Kernel 1: projection for ONE of q/k/v.  C[8192,1152] = X(bf16) @ Wg + bg.
// Plain bf16 MFMA; all staging full-wave global_load_lds.
// Grid (64 m, 9 n): A-tile sharers at linear-ID stride 64 -> same XCD.
// which==2 (V): stored transposed [bh][d][s], chunk-swizzled within each
// 64-s block (chunk ^= d&7) so attn can load linearly + XOR on read.
// ---------------------------------------------------------------------------
__global__ __launch_bounds__(256)
void qkv_proj_one(const short* __restrict__ Xb, const short* __restrict__ WTn,
                  const float* __restrict__ bias, short* __restrict__ qkvW, int which)
{
    __shared__ short aT[128][32], bW[128][32];
    const int tid = threadIdx.x, lane = tid & 63, w = tid >> 6;
    const int c = lane & 15, g = lane >> 4;
    const int m0 = blockIdx.x * 128, n0 = blockIdx.y * 128;
    const int wm = (w >> 1) * 64, wn = (w & 1) * 64;
    const int lrow = lane >> 2, lch = (lane & 3) * 8;

    f32x4 acc[4][4] = {};

    for (int k0 = 0; k0 < E; k0 += 32) {
        __syncthreads();
        for (int t = 0; t < 2; ++t) {
            int row = w * 32 + t * 16;
            gload_lds16(Xb + (long)(m0 + row + lrow) * E + k0 + lch, &aT[row][0]);
            gload_lds16(WTn + (long)(n0 + row + lrow) * E + k0 + lch, &bW[row][0]);
        }
        __syncthreads();

        bf16x8 af[4], bh[4];
        for (int i = 0; i < 4; ++i) {
            af[i] = *reinterpret_cast<const bf16x8*>(&aT[wm + i * 16 + c][g * 8]);
            bh[i] = *reinterpret_cast<const bf16x8*>(&bW[wn + i * 16 + c][g * 8]);
        }
        for (int i = 0; i < 4; ++i)
            for (int j = 0; j < 4; ++j)
                acc[i][j] = MFMA16(af[i], bh[j], acc[i][j]);
    }

    for (int j = 0; j < 4; ++j) {
        int n = n0 + wn + j * 16 + c;      // 0..1151
        float bv = bias[n];
        int hh = n / D, dd = n % D;
        if (which < 2) {
            for (int i = 0; i < 4; ++i) {
                int rowb = m0 + wm + i * 16 + g * 4;
                for (int r = 0; r < 4; ++r) {
                    int row = rowb + r;
                    int b = row >> 10, s = row & 1023;
                    qkvW[((long)(b * H + hh) * S + s) * D + dd] = f2bf(acc[i][j][r] + bv);
                }
            }
        } else {
            int cx = dd & 7;
            for (int i = 0; i < 4; ++i) {
                int srow = m0 + wm + i * 16 + g * 4;   // 4 consecutive s
                int b = srow >> 10, s = srow & 1023;
                int sw = (s & ~63) | ((((s >> 3) & 7) ^ cx) << 3) | (s & 7);
                bf16x4 pk = {f2bf(acc[i][j][0] + bv), f2bf(acc[i][j][1] + bv),
                             f2bf(acc[i][j][2] + bv), f2bf(acc[i][j][3] + bv)};
                *reinterpret_cast<bf16x4*>(&qkvW[((long)(b * H + hh) * D + dd) * S + sw]) = pk;
            }
        }
    }
}

// ---------------------------------------------------------------------------
// Kernel 2: flash attention (r17-proven version).  q-tile 256, 8 waves/block,
// grid (bh, 4) = 512 blocks (grid-limited to 2 blocks/CU — the r18/r19
// i-split lesson: LDS savings can't raise occupancy past the grid cap, and
// per-i PV doubles V LDS reads; the two-i form is measured-faster).
// Swapped-operand (S^T = K Q^T) + fixed-offset softmax p = 2^(s*K2 - 4).
// l via MFMA ones-row (V^T pad row 72 = 1.0 -> accO[4] reg0 @ lanes 32..47).
// LDS (shorts): K[64][72]@0 | guard 24 @4608 | V[80][64]@4632 (row72=ones,
// 73..79 zero) | PT dwords @9752 (9216 dw).  Total 56368 B.
// ---------------------------------------------------------------------------
__global__ __launch_bounds__(512, 4)
void attn_fwd(const short* __restrict__ qkv, short* __restrict__ attn)
{
    __shared__ short smem[28184];
    unsigned* PT = reinterpret_cast<unsigned*>(smem + 9752);
    const int tid = threadIdx.x, lane = tid & 63, w = tid >> 6;   // w: 0..7
    const int c = lane & 15, g = lane >> 4;
    const int bh = blockIdx.x;
    const int q0 = blockIdx.y * 256;
    const int b = bh >> 4, h = bh & 15;

    const short* Qb = qkv + (long)bh * (S * D);
    const short* Kb = qkv + QKV_T + (long)bh * (S * D);
    const short* Vt = qkv + 2 * QKV_T + (long)bh * ((long)D * S);

    // zero K guard; V pad: row 72 = bf16 1.0 (l-accumulator row), 73..79 = 0
    if (tid < 24) smem[4608 + tid] = 0;
    if (tid < 512) smem[9240 + tid] = (tid < 64) ? (short)0x3F80 : (short)0;

    // staging descriptors (rounds r = w + rr*8, r < 9)
    const short* kg[2]; const short* vg[2]; int ldsOff[2];
    #pragma unroll
    for (int rr = 0; rr < 2; ++rr) {
        int r = w + rr * 8;
        int id = r * 64 + lane;
        kg[rr] = Kb + id * 8;
        vg[rr] = Vt + (long)(id >> 3) * S + (id & 7) * 8;
        ldsOff[rr] = id * 8;
    }

    // Q fragments (B-operand), d-tail zero for g>0
    bf16x8 qf[2][3];
    const bf16x8 zf = {};
    for (int i = 0; i < 2; ++i) {
        const short* qr = Qb + (long)(q0 + w * 32 + i * 16 + c) * D;
        qf[i][0] = *reinterpret_cast<const bf16x8*>(qr + g * 8);
        qf[i][1] = *reinterpret_cast<const bf16x8*>(qr + 32 + g * 8);
        qf[i][2] = (g == 0) ? *reinterpret_cast<const bf16x8*>(qr + 64) : zf;
    }

    const float K2 = 0.17003594880664552f;   // 72^-0.5 * log2(e)
    const float M2 = 4.0f;                   // fixed exp2-domain offset
    f32x4 accO[5][2] = {};

    for (int kt = 0; kt < 16; ++kt) {
        __syncthreads();   // prior tile's reads done
        #pragma unroll
        for (int rr = 0; rr < 2; ++rr) {
            if (w + rr * 8 < 9) {
                gload_lds16(kg[rr], &smem[ldsOff[rr]]);
                gload_lds16(vg[rr], &smem[4632 + ldsOff[rr]]);
                kg[rr] += 64 * D;
                vg[rr] += 64;
            }
        }
        __syncthreads();

        // ---- S^T[k'][q] = K Q^T ----
        f32x4 sT[4][2] = {};
        for (int dc = 0; dc < 3; ++dc) {
            for (int j = 0; j < 4; ++j) {
                bf16x8 kf = *reinterpret_cast<const bf16x8*>(
                    &smem[(j * 16 + c) * 72 + dc * 32 + g * 8]);
                for (int i = 0; i < 2; ++i)
                    sT[j][i] = MFMA16(kf, qf[i][dc], sT[j][i]);
            }
        }

        // ---- fixed-offset softmax: p = 2^(s*K2 - M2); no max, no row-sum ----
        for (int i = 0; i < 2; ++i) {
            for (int j = 0; j < 4; ++j) {
                float p0 = exp2f(fmaf(sT[j][i][0], K2, -M2));
                float p1 = exp2f(fmaf(sT[j][i][1], K2, -M2));
                float p2 = exp2f(fmaf(sT[j][i][2], K2, -M2));
                float p3 = exp2f(fmaf(sT[j][i][3], K2, -M2));
                uint2 pw = {cvtpk(p0, p1), cvtpk(p2, p3)};
                *reinterpret_cast<uint2*>(
                    &PT[((w * 2 + i) * 16 + c) * 36 + j * 8 + g * 2]) = pw;
            }
        }

        // ---- O^T[d][q] += V^T P^T  (V slot XOR matches storage swizzle;
        //      row 72 of V^T = ones -> accO[4] reg0 accumulates l) ----
        for (int ks = 0; ks < 2; ++ks) {
            bf16x8 pf[2];
            for (int i = 0; i < 2; ++i)
                pf[i] = *reinterpret_cast<const bf16x8*>(
                    &PT[((w * 2 + i) * 16 + c) * 36 + ks * 16 + g * 4]);
            for (int n = 0; n < 5; ++n) {
                bf16x8 vf = *reinterpret_cast<const bf16x8*>(
                    &smem[4632 + (n * 16 + c) * 64 + (((ks * 4 + g) ^ (c & 7))) * 8]);
                for (int i = 0; i < 2; ++i)
                    accO[n][i] = MFMA16(vf, pf[i], accO[n][i]);
            }
        }
    }

    // ---- epilogue: l = accO[4][i][0] at lane 32+c; stage O[256][72], burst ----
    __syncthreads();   // all waves done reading K/V LDS
    for (int i = 0; i < 2; ++i) {
        float lv = __shfl(accO[4][i][0], 32 + c);
        float inv = 1.f / lv;
        int ql = w * 32 + i * 16 + c;          // 0..255
        for (int n = 0; n < 5; ++n) {
            int d0 = n * 16 + g * 4;
            if (d0 >= D) continue;
            uint2 pk = {cvtpk(accO[n][i][0] * inv, accO[n][i][1] * inv),
                        cvtpk(accO[n][i][2] * inv, accO[n][i][3] * inv)};
            *reinterpret_cast<uint2*>(&smem[ql * 72 + d0]) = pk;
        }
    }
    __syncthreads();
    {
        const long rowbase = (long)(b * S + q0) * E + h * D;
        for (int ch = tid; ch < 2304; ch += 512) {
            int row = ch / 9, off = (ch % 9) * 8;
            *reinterpret_cast<uint4*>(attn + rowbase + (long)row * E + off) =
                *reinterpret_cast<const uint4*>(&smem[row * 72 + off]);
        }
    }
}

// ---------------------------------------------------------------------------
// Kernel 3: out projection.  out[8192,1152] = attn(bf16) @ WTo(bf16) + b.
// Grid (64 m, 9 n) — same XCD-locality argument as qkv_proj_one.
// ---------------------------------------------------------------------------
__global__ __launch_bounds__(256)
void out_proj(const short* __restrict__ Aat, const short* __restrict__ WTo,
              const float* __restrict__ bias, float* __restrict__ out)
{
    __shared__ short aT[128][32], bT[128][32];
    const int tid = threadIdx.x, lane = tid & 63, w = tid >> 6;
    const int c = lane & 15, g = lane >> 4;
    const int m0 = blockIdx.x * 128, n0 = blockIdx.y * 128;
    const int wm = (w >> 1) * 64, wn = (w & 1) * 64;
    const int lrow = lane >> 2, lch = (lane & 3) * 8;

    f32x4 acc[4][4] = {};
    for (int k0 = 0; k0 < E; k0 += 32) {
        __syncthreads();
        for (int t = 0; t < 2; ++t) {
            int row = w * 32 + t * 16;
            gload_lds16(Aat + (long)(m0 + row + lrow) * E + k0 + lch, &aT[row][0]);
            gload_lds16(WTo + (long)(n0 + row + lrow) * E + k0 + lch, &bT[row][0]);
        }
        __syncthreads();

        bf16x8 af[4], bf[4];
        for (int i = 0; i < 4; ++i) {
            af[i] = *reinterpret_cast<const bf16x8*>(&aT[wm + i * 16 + c][g * 8]);
            bf[i] = *reinterpret_cast<const bf16x8*>(&bT[wn + i * 16 + c][g * 8]);
        }
        for (int i = 0; i < 4; ++i)
            for (int j = 0; j < 4; ++j)
                acc[i][j] = MFMA16(af[i], bf[j], acc[i][j]);
    }

    for (int j = 0; j < 4; ++j) {
        int n = n0 + wn + j * 16 + c;
        float bv = bias[n];
        for (int i = 0; i < 4; ++i)
            for (int r = 0; r < 4; ++r) {
                int row = m0 + wm + i * 16 + g * 4 + r;
                out[(long)row * E + n] = acc[i][j][r] + bv;
            }
    }
}

// ---------------------------------------------------------------------------
// Workspace (shorts), peak 83.46 MB:
//   Q[QKV_T] | K[QKV_T] | V^T[QKV_T] | A[QKV_T] | WT[3456*1152]
// A slot: bf16-converted input during projections (conv->proj interleaved to
// keep the 18.9 MB input hot in L2), then attn output.  WTo aliases WT.
// ---------------------------------------------------------------------------
extern "C" void kernel_launch(void* const* d_in, const int* in_sizes, int n_in,
                              void* d_out, int out_size, void* d_ws, size_t ws_size,
                              hipStream_t stream)
{
    const float* qin   = (const float*)d_in[0];
    const float* kin   = (const float*)d_in[1];
    const float* vin   = (const float*)d_in[2];
    const float* w_in  = (const float*)d_in[3];
    const float* b_in  = (const float*)d_in[4];
    const float* w_out = (const float*)d_in[5];
    const float* b_out = (const float*)d_in[6];

    short* ws  = (short*)d_ws;
    short* Q   = ws;
    short* K   = ws + QKV_T;
    short* V   = ws + 2 * QKV_T;
    short* A   = ws + 3 * QKV_T;   // converted input, then attn output
    short* WT  = ws + 4 * QKV_T;
    short* WTo = WT;
    float* out = (float*)d_out;

    wt_conv<<<dim3(108, 36), 256, 0, stream>>>(w_in, WT, E, N3);

    tobf16<<<2048, 256, 0, stream>>>(vin, A, QKV_T / 4);
    qkv_proj_one<<<dim3(64, 9), 256, 0, stream>>>(A, WT + 2L * E * E, b_in + 2 * E, V, 2);
    tobf16<<<2048, 256, 0, stream>>>(kin, A, QKV_T / 4);
    qkv_proj_one<<<dim3(64, 9), 256, 0, stream>>>(A, WT + 1L * E * E, b_in + E, K, 1);
    tobf16<<<2048, 256, 0, stream>>>(qin, A, QKV_T / 4);
    qkv_proj_one<<<dim3(64, 9), 256, 0, stream>>>(A, WT, b_in, Q, 0);

    attn_fwd<<<dim3(128, 4), 512, 0, stream>>>(ws, A);
    wt_conv<<<dim3(36, 36), 256, 0, stream>>>(w_out, WTo, E, E);
    out_proj<<<dim3(64, 9), 256, 0, stream>>>(A, WTo, b_out, out);
}

// Round 21
// 227.824 us; speedup vs baseline: 2.7358x; 1.0335x over previous
//
#include <hip/hip_runtime.h>
#include <hip/hip_bf16.h>
#include <math.h>
#include <stdint.h>

// Problem constants
static constexpr int Bb = 8, S = 1024, E = 1152, H = 16, D = 72;
static constexpr int N3 = 3 * E;                 // 3456
static constexpr long QKV_T = (long)Bb * H * S * D;  // 9437184 elems per tensor

typedef __attribute__((ext_vector_type(8))) short bf16x8;
typedef __attribute__((ext_vector_type(4))) short bf16x4;
typedef __attribute__((ext_vector_type(4))) float f32x4;

#define MFMA16(A, B, C) __builtin_amdgcn_mfma_f32_16x16x32_bf16(A, B, C, 0, 0, 0)

__device__ __forceinline__ short f2bf(float f) {
    __hip_bfloat16 h = __float2bfloat16(f);
    return __builtin_bit_cast(short, h);
}
// HW packed f32->bf16 (RNE)
__device__ __forceinline__ unsigned cvtpk(float lo, float hi) {
    unsigned r;
    asm("v_cvt_pk_bf16_f32 %0, %1, %2" : "=v"(r) : "v"(lo), "v"(hi));
    return r;
}

__device__ __forceinline__ void gload_lds16(const void* g, void* l) {
    __builtin_amdgcn_global_load_lds(
        (const __attribute__((address_space(1))) unsigned int*)g,
        (__attribute__((address_space(3))) unsigned int*)l, 16, 0, 0);
}

// ---------------------------------------------------------------------------
// Kernel A: transpose+convert.  W[K][N] f32 -> WT[N][K] bf16.
// ---------------------------------------------------------------------------
__global__ __launch_bounds__(256)
void wt_conv(const float* __restrict__ W, short* __restrict__ WT, int K, int N)
{
    __shared__ float tt[32][33];
    const int n0 = blockIdx.x * 32, k0 = blockIdx.y * 32;
    const int t = threadIdx.x;
    {
        int r = t >> 3, c4 = (t & 7) * 4;
        float4 v = *reinterpret_cast<const float4*>(W + (long)(k0 + r) * N + n0 + c4);
        tt[r][c4 + 0] = v.x; tt[r][c4 + 1] = v.y; tt[r][c4 + 2] = v.z; tt[r][c4 + 3] = v.w;
    }
    __syncthreads();
    {
        int n = t >> 3, k4 = (t & 7) * 4;
        bf16x4 o = {f2bf(tt[k4 + 0][n]), f2bf(tt[k4 + 1][n]),
                    f2bf(tt[k4 + 2][n]), f2bf(tt[k4 + 3][n])};
        *reinterpret_cast<bf16x4*>(WT + (long)(n0 + n) * K + k0 + k4) = o;
    }
}

// ---------------------------------------------------------------------------
// Kernel B: convert f32 -> bf16.  n4 = element_count / 4.
// ---------------------------------------------------------------------------
__global__ __launch_bounds__(256)
void tobf16(const float* __restrict__ X, short* __restrict__ Y, long n4)
{
    for (long i = (long)blockIdx.x * 256 + threadIdx.x; i < n4; i += (long)gridDim.x * 256) {
        float4 v = reinterpret_cast<const float4*>(X)[i];
        uint2 p = {cvtpk(v.x, v.y), cvtpk(v.z, v.w)};
        reinterpret_cast<uint2*>(Y)[i] = p;
    }
}

// ---------------------------------------------------------------------------
// Kernel 1: projection for ONE of q/k/v.  C[8192,1152] = X(bf16) @ Wg + bg.
// Plain bf16 MFMA; all staging full-wave global_load_lds.
// Grid (64 m, 9 n): A-tile sharers at linear-ID stride 64 -> same XCD.
// which==2 (V): stored transposed [bh][d][s], chunk-swizzled within each
// 64-s block (chunk ^= d&7) so attn can load linearly + XOR on read.
// ---------------------------------------------------------------------------
__global__ __launch_bounds__(256)
void qkv_proj_one(const short* __restrict__ Xb, const short* __restrict__ WTn,
                  const float* __restrict__ bias, short* __restrict__ qkvW, int which)
{
    __shared__ short aT[128][32], bW[128][32];
    const int tid = threadIdx.x, lane = tid & 63, w = tid >> 6;
    const int c = lane & 15, g = lane >> 4;
    const int m0 = blockIdx.x * 128, n0 = blockIdx.y * 128;
    const int wm = (w >> 1) * 64, wn = (w & 1) * 64;
    const int lrow = lane >> 2, lch = (lane & 3) * 8;

    f32x4 acc[4][4] = {};

    for (int k0 = 0; k0 < E; k0 += 32) {
        __syncthreads();
        for (int t = 0; t < 2; ++t) {
            int row = w * 32 + t * 16;
            gload_lds16(Xb + (long)(m0 + row + lrow) * E + k0 + lch, &aT[row][0]);
            gload_lds16(WTn + (long)(n0 + row + lrow) * E + k0 + lch, &bW[row][0]);
        }
        __syncthreads();

        bf16x8 af[4], bh[4];
        for (int i = 0; i < 4; ++i) {
            af[i] = *reinterpret_cast<const bf16x8*>(&aT[wm + i * 16 + c][g * 8]);
            bh[i] = *reinterpret_cast<const bf16x8*>(&bW[wn + i * 16 + c][g * 8]);
        }
        for (int i = 0; i < 4; ++i)
            for (int j = 0; j < 4; ++j)
                acc[i][j] = MFMA16(af[i], bh[j], acc[i][j]);
    }

    for (int j = 0; j < 4; ++j) {
        int n = n0 + wn + j * 16 + c;      // 0..1151
        float bv = bias[n];
        int hh = n / D, dd = n % D;
        if (which < 2) {
            for (int i = 0; i < 4; ++i) {
                int rowb = m0 + wm + i * 16 + g * 4;
                for (int r = 0; r < 4; ++r) {
                    int row = rowb + r;
                    int b = row >> 10, s = row & 1023;
                    qkvW[((long)(b * H + hh) * S + s) * D + dd] = f2bf(acc[i][j][r] + bv);
                }
            }
        } else {
            int cx = dd & 7;
            for (int i = 0; i < 4; ++i) {
                int srow = m0 + wm + i * 16 + g * 4;   // 4 consecutive s
                int b = srow >> 10, s = srow & 1023;
                int sw = (s & ~63) | ((((s >> 3) & 7) ^ cx) << 3) | (s & 7);
                bf16x4 pk = {f2bf(acc[i][j][0] + bv), f2bf(acc[i][j][1] + bv),
                             f2bf(acc[i][j][2] + bv), f2bf(acc[i][j][3] + bv)};
                *reinterpret_cast<bf16x4*>(&qkvW[((long)(b * H + hh) * D + dd) * S + sw]) = pk;
            }
        }
    }
}

// ---------------------------------------------------------------------------
// Kernel 2: flash attention, q-tile 256, 8 waves/block, grid (bh, 4).
// Swapped-operand (S^T = K Q^T) + fixed-offset softmax p = 2^(s*K2 - 4).
// l via MFMA ones-row (V^T pad row 72 = 1.0 -> accO[4] reg0 @ lanes 32..47).
// r21: T3 2-phase double-buffered staging — per tile: issue gloads for kt+1
// into buf^1, compute buf, ONE barrier (its implicit vmcnt(0) drains loads
// that flew under the whole compute phase).  Was: 2 barriers + exposed drain.
// LDS (shorts): buf0 {K[64][72]@0|guard@4608|V[80][64]@4632} | buf1 @9752 |
// PT dwords @19504.  Total 75872 B -> 2 blocks/CU (unchanged occupancy).
// ---------------------------------------------------------------------------
__global__ __launch_bounds__(512, 4)
void attn_fwd(const short* __restrict__ qkv, short* __restrict__ attn)
{
    __shared__ short smem[37936];
    unsigned* PT = reinterpret_cast<unsigned*>(smem + 19504);
    const int tid = threadIdx.x, lane = tid & 63, w = tid >> 6;   // w: 0..7
    const int c = lane & 15, g = lane >> 4;
    const int bh = blockIdx.x;
    const int q0 = blockIdx.y * 256;
    const int b = bh >> 4, h = bh & 15;

    const short* Qb = qkv + (long)bh * (S * D);
    const short* Kb = qkv + QKV_T + (long)bh * (S * D);
    const short* Vt = qkv + 2 * QKV_T + (long)bh * ((long)D * S);

    // both buffers: K guard = 0; V row 72 = bf16 1.0 (l-row), rows 73..79 = 0
    if (tid < 24) { smem[4608 + tid] = 0; smem[9752 + 4608 + tid] = 0; }
    if (tid < 512) {
        short pv = (tid < 64) ? (short)0x3F80 : (short)0;
        smem[9240 + tid] = pv;
        smem[9752 + 9240 + tid] = pv;
    }

    // staging descriptors (rounds r = w + rr*8, r < 9)
    const short* kg[2]; const short* vg[2]; int ldsOff[2];
    #pragma unroll
    for (int rr = 0; rr < 2; ++rr) {
        int r = w + rr * 8;
        int id = r * 64 + lane;
        kg[rr] = Kb + id * 8;
        vg[rr] = Vt + (long)(id >> 3) * S + (id & 7) * 8;
        ldsOff[rr] = id * 8;
    }

    // Q fragments (B-operand), d-tail zero for g>0
    bf16x8 qf[2][3];
    const bf16x8 zf = {};
    for (int i = 0; i < 2; ++i) {
        const short* qr = Qb + (long)(q0 + w * 32 + i * 16 + c) * D;
        qf[i][0] = *reinterpret_cast<const bf16x8*>(qr + g * 8);
        qf[i][1] = *reinterpret_cast<const bf16x8*>(qr + 32 + g * 8);
        qf[i][2] = (g == 0) ? *reinterpret_cast<const bf16x8*>(qr + 64) : zf;
    }

    const float K2 = 0.17003594880664552f;   // 72^-0.5 * log2(e)
    const float M2 = 4.0f;                   // fixed exp2-domain offset
    f32x4 accO[5][2] = {};

    // prologue: stage tile 0 into buf0, advance pointers
    #pragma unroll
    for (int rr = 0; rr < 2; ++rr) {
        if (w + rr * 8 < 9) {
            gload_lds16(kg[rr], &smem[ldsOff[rr]]);
            gload_lds16(vg[rr], &smem[4632 + ldsOff[rr]]);
            kg[rr] += 64 * D;
            vg[rr] += 64;
        }
    }
    __syncthreads();

    int bufOff = 0;
    for (int kt = 0; kt < 16; ++kt) {
        const int nextOff = bufOff ^ 9752;
        // issue next tile's loads FIRST — they fly under this tile's compute
        if (kt < 15) {
            #pragma unroll
            for (int rr = 0; rr < 2; ++rr) {
                if (w + rr * 8 < 9) {
                    gload_lds16(kg[rr], &smem[nextOff + ldsOff[rr]]);
                    gload_lds16(vg[rr], &smem[nextOff + 4632 + ldsOff[rr]]);
                    kg[rr] += 64 * D;
                    vg[rr] += 64;
                }
            }
        }

        // ---- S^T[k'][q] = K Q^T ----
        f32x4 sT[4][2] = {};
        for (int dc = 0; dc < 3; ++dc) {
            for (int j = 0; j < 4; ++j) {
                bf16x8 kf = *reinterpret_cast<const bf16x8*>(
                    &smem[bufOff + (j * 16 + c) * 72 + dc * 32 + g * 8]);
                for (int i = 0; i < 2; ++i)
                    sT[j][i] = MFMA16(kf, qf[i][dc], sT[j][i]);
            }
        }

        // ---- fixed-offset softmax: p = 2^(s*K2 - M2) ----
        for (int i = 0; i < 2; ++i) {
            for (int j = 0; j < 4; ++j) {
                float p0 = exp2f(fmaf(sT[j][i][0], K2, -M2));
                float p1 = exp2f(fmaf(sT[j][i][1], K2, -M2));
                float p2 = exp2f(fmaf(sT[j][i][2], K2, -M2));
                float p3 = exp2f(fmaf(sT[j][i][3], K2, -M2));
                uint2 pw = {cvtpk(p0, p1), cvtpk(p2, p3)};
                *reinterpret_cast<uint2*>(
                    &PT[((w * 2 + i) * 16 + c) * 36 + j * 8 + g * 2]) = pw;
            }
        }

        // ---- O^T[d][q] += V^T P^T  (V slot XOR matches storage swizzle;
        //      row 72 of V^T = ones -> accO[4] reg0 accumulates l) ----
        for (int ks = 0; ks < 2; ++ks) {
            bf16x8 pf[2];
            for (int i = 0; i < 2; ++i)
                pf[i] = *reinterpret_cast<const bf16x8*>(
                    &PT[((w * 2 + i) * 16 + c) * 36 + ks * 16 + g * 4]);
            for (int n = 0; n < 5; ++n) {
                bf16x8 vf = *reinterpret_cast<const bf16x8*>(
                    &smem[bufOff + 4632 + (n * 16 + c) * 64 +
                          (((ks * 4 + g) ^ (c & 7))) * 8]);
                for (int i = 0; i < 2; ++i)
                    accO[n][i] = MFMA16(vf, pf[i], accO[n][i]);
            }
        }

        __syncthreads();   // drains next-tile loads (flew under compute) +
                           // protects buf reuse; the ONLY barrier per tile
        bufOff = nextOff;
    }

    // ---- epilogue: l = accO[4][i][0] at lane 32+c; stage O[256][72], burst ----
    for (int i = 0; i < 2; ++i) {
        float lv = __shfl(accO[4][i][0], 32 + c);
        float inv = 1.f / lv;
        int ql = w * 32 + i * 16 + c;          // 0..255
        for (int n = 0; n < 5; ++n) {
            int d0 = n * 16 + g * 4;
            if (d0 >= D) continue;
            uint2 pk = {cvtpk(accO[n][i][0] * inv, accO[n][i][1] * inv),
                        cvtpk(accO[n][i][2] * inv, accO[n][i][3] * inv)};
            *reinterpret_cast<uint2*>(&smem[ql * 72 + d0]) = pk;
        }
    }
    __syncthreads();
    {
        const long rowbase = (long)(b * S + q0) * E + h * D;
        for (int ch = tid; ch < 2304; ch += 512) {
            int row = ch / 9, off = (ch % 9) * 8;
            *reinterpret_cast<uint4*>(attn + rowbase + (long)row * E + off) =
                *reinterpret_cast<const uint4*>(&smem[row * 72 + off]);
        }
    }
}

// ---------------------------------------------------------------------------
// Kernel 3: out projection.  out[8192,1152] = attn(bf16) @ WTo(bf16) + b.
// Grid (64 m, 9 n) — same XCD-locality argument as qkv_proj_one.
// ---------------------------------------------------------------------------
__global__ __launch_bounds__(256)
void out_proj(const short* __restrict__ Aat, const short* __restrict__ WTo,
              const float* __restrict__ bias, float* __restrict__ out)
{
    __shared__ short aT[128][32], bT[128][32];
    const int tid = threadIdx.x, lane = tid & 63, w = tid >> 6;
    const int c = lane & 15, g = lane >> 4;
    const int m0 = blockIdx.x * 128, n0 = blockIdx.y * 128;
    const int wm = (w >> 1) * 64, wn = (w & 1) * 64;
    const int lrow = lane >> 2, lch = (lane & 3) * 8;

    f32x4 acc[4][4] = {};
    for (int k0 = 0; k0 < E; k0 += 32) {
        __syncthreads();
        for (int t = 0; t < 2; ++t) {
            int row = w * 32 + t * 16;
            gload_lds16(Aat + (long)(m0 + row + lrow) * E + k0 + lch, &aT[row][0]);
            gload_lds16(WTo + (long)(n0 + row + lrow) * E + k0 + lch, &bT[row][0]);
        }
        __syncthreads();

        bf16x8 af[4], bf[4];
        for (int i = 0; i < 4; ++i) {
            af[i] = *reinterpret_cast<const bf16x8*>(&aT[wm + i * 16 + c][g * 8]);
            bf[i] = *reinterpret_cast<const bf16x8*>(&bT[wn + i * 16 + c][g * 8]);
        }
        for (int i = 0; i < 4; ++i)
            for (int j = 0; j < 4; ++j)
                acc[i][j] = MFMA16(af[i], bf[j], acc[i][j]);
    }

    for (int j = 0; j < 4; ++j) {
        int n = n0 + wn + j * 16 + c;
        float bv = bias[n];
        for (int i = 0; i < 4; ++i)
            for (int r = 0; r < 4; ++r) {
                int row = m0 + wm + i * 16 + g * 4 + r;
                out[(long)row * E + n] = acc[i][j][r] + bv;
            }
    }
}

// ---------------------------------------------------------------------------
// Workspace (shorts), peak 83.46 MB:
//   Q[QKV_T] | K[QKV_T] | V^T[QKV_T] | A[QKV_T] | WT[3456*1152]
// A slot: bf16-converted input during projections (conv->proj interleaved to
// keep the 18.9 MB input hot in L2), then attn output.  WTo aliases WT.
// ---------------------------------------------------------------------------
extern "C" void kernel_launch(void* const* d_in, const int* in_sizes, int n_in,
                              void* d_out, int out_size, void* d_ws, size_t ws_size,
                              hipStream_t stream)
{
    const float* qin   = (const float*)d_in[0];
    const float* kin   = (const float*)d_in[1];
    const float* vin   = (const float*)d_in[2];
    const float* w_in  = (const float*)d_in[3];
    const float* b_in  = (const float*)d_in[4];
    const float* w_out = (const float*)d_in[5];
    const float* b_out = (const float*)d_in[6];

    short* ws  = (short*)d_ws;
    short* Q   = ws;
    short* K   = ws + QKV_T;
    short* V   = ws + 2 * QKV_T;
    short* A   = ws + 3 * QKV_T;   // converted input, then attn output
    short* WT  = ws + 4 * QKV_T;
    short* WTo = WT;
    float* out = (float*)d_out;

    wt_conv<<<dim3(108, 36), 256, 0, stream>>>(w_in, WT, E, N3);

    tobf16<<<2048, 256, 0, stream>>>(vin, A, QKV_T / 4);
    qkv_proj_one<<<dim3(64, 9), 256, 0, stream>>>(A, WT + 2L * E * E, b_in + 2 * E, V, 2);
    tobf16<<<2048, 256, 0, stream>>>(kin, A, QKV_T / 4);
    qkv_proj_one<<<dim3(64, 9), 256, 0, stream>>>(A, WT + 1L * E * E, b_in + E, K, 1);
    tobf16<<<2048, 256, 0, stream>>>(qin, A, QKV_T / 4);
    qkv_proj_one<<<dim3(64, 9), 256, 0, stream>>>(A, WT, b_in, Q, 0);

    attn_fwd<<<dim3(128, 4), 512, 0, stream>>>(ws, A);
    wt_conv<<<dim3(36, 36), 256, 0, stream>>>(w_out, WTo, E, E);
    out_proj<<<dim3(64, 9), 256, 0, stream>>>(A, WTo, b_out, out);
}